// Round 12
// baseline (194.689 us; speedup 1.0000x reference)
//
#include <hip/hip_runtime.h>
#include <hip/hip_bf16.h>

// Fixed shape: B=4096, I=1024, H=1024
#define B_ROWS 4096
#define H_DIM  1024
#define K_DIM  2048   // I + H
#define N_DIM  4096   // 4H
#define NT32   64     // K_DIM / 32 K-tiles

typedef __attribute__((ext_vector_type(8))) short bf16x8;
typedef __attribute__((ext_vector_type(4))) float f32x4;

__device__ __forceinline__ unsigned short f2bf(float f) {
  union { float f; unsigned int u; } v; v.f = f;
  unsigned int u = v.u;
  return (unsigned short)((u + 0x7fffu + ((u >> 16) & 1u)) >> 16);
}
__device__ __forceinline__ float bf2f(unsigned short u) {
  union { unsigned int u; float f; } v; v.u = ((unsigned int)u) << 16;
  return v.f;
}

// -------- GEMM with fused fp32->bf16 staging (NO pack kernel) --------------
// gates(bf16) = concat(x,h)(fp32) * W^T(fp32) + bias, inputs converted to
// bf16 in-register during staging.
// 256x256 tile, BK=32, 8 waves (2x4), wave-tile 128x64, 4 x 32KB LDS bufs
// (A 16KB + B 16KB; 16x32-bf16 subtiles of 1KB, st_16x32 XOR swizzle).
// Reg-staging: per wave 8 global_load_dwordx4 (fp32) -> f2bf -> 4 swizzled
// ds_write_b128. Writer layout == reader layout (both (r*64+m*16)^((r&8)<<2)).
// Per tile t: vmcnt(0)[loads(t+1), landed] -> cvt+write -> buf[(t+1)&3]
//   -> issue loads(t+2) -> 12 ds_read frags(t) from buf[t&3]
//   -> lgkmcnt(0) -> 32 MFMA -> barrier.
// Race-free: writes(t+1) vs frag reads(t+1) separated by the tile-end
// barrier; buf[(t+1)&3] last read at tile t-3 (3 barriers ago).

#define UNR _Pragma("unroll")

// issue 8 fp32 loads for K-tile kt into LA/LB (per wave: A 2 subtiles,
// B 2 subtiles; lane covers row l>>2, cols (l&3)*8 .. +7 of each subtile)
#define ISSUE_LOADS(kt)                                                      \
  {                                                                          \
    const int kk = (kt);                                                     \
    const float* a0 = (kk < 32) ? (pAx0 + kk * 32) : (pAh0 + (kk - 32) * 32);\
    const float* a1 = (kk < 32) ? (pAx1 + kk * 32) : (pAh1 + (kk - 32) * 32);\
    LA00 = *(const float4*)(a0);                                             \
    LA01 = *(const float4*)(a0 + 4);                                         \
    LA10 = *(const float4*)(a1);                                             \
    LA11 = *(const float4*)(a1 + 4);                                         \
    LB00 = *(const float4*)(pB0 + kk * 32);                                  \
    LB01 = *(const float4*)(pB0 + kk * 32 + 4);                              \
    LB10 = *(const float4*)(pB1 + kk * 32);                                  \
    LB11 = *(const float4*)(pB1 + kk * 32 + 4);                              \
  }

#define PK8(dst, v0, v1)                                                     \
  {                                                                          \
    bf16x8 pk;                                                               \
    pk[0] = (short)f2bf(v0.x); pk[1] = (short)f2bf(v0.y);                    \
    pk[2] = (short)f2bf(v0.z); pk[3] = (short)f2bf(v0.w);                    \
    pk[4] = (short)f2bf(v1.x); pk[5] = (short)f2bf(v1.y);                    \
    pk[6] = (short)f2bf(v1.z); pk[7] = (short)f2bf(v1.w);                    \
    *(bf16x8*)(dst) = pk;                                                    \
  }

// cvt + write current LA/LB into LDS buffer at BUFOFS
#define CVT_WRITE(BUFOFS)                                                    \
  {                                                                          \
    char* const Lw = lds + (BUFOFS);                                         \
    PK8(Lw + (2 * w + 0) * 1024 + wofs, LA00, LA01);                         \
    PK8(Lw + (2 * w + 1) * 1024 + wofs, LA10, LA11);                         \
    PK8(Lw + 16384 + (2 * w + 0) * 1024 + wofs, LB00, LB01);                 \
    PK8(Lw + 16384 + (2 * w + 1) * 1024 + wofs, LB10, LB11);                 \
  }

#define TILE1(tt, BUF)                                                       \
  {                                                                          \
    asm volatile("s_waitcnt vmcnt(0)" ::: "memory");                         \
    __builtin_amdgcn_sched_barrier(0);                                       \
    CVT_WRITE((((BUF) + 1) & 3) * 32768);                                    \
    __builtin_amdgcn_sched_barrier(0);                                       \
    ISSUE_LOADS(((tt) + 2) & (NT32 - 1));                                    \
    const char* const Lc = lds + (BUF) * 32768;                              \
    bf16x8 aF[8], bF[4];                                                     \
    UNR for (int mi = 0; mi < 8; ++mi)                                       \
      aF[mi] = *(const bf16x8*)(Lc + (wm * 8 + mi) * 1024 + lofs);           \
    UNR for (int ni = 0; ni < 4; ++ni)                                       \
      bF[ni] = *(const bf16x8*)(Lc + 16384 + (wn * 4 + ni) * 1024 + lofs);   \
    asm volatile("s_waitcnt lgkmcnt(0)" ::: "memory");                       \
    __builtin_amdgcn_sched_barrier(0);                                       \
    __builtin_amdgcn_s_setprio(1);                                           \
    UNR for (int mi = 0; mi < 8; ++mi)                                       \
      UNR for (int ni = 0; ni < 4; ++ni)                                     \
        acc[mi][ni] = __builtin_amdgcn_mfma_f32_16x16x32_bf16(               \
            aF[mi], bF[ni], acc[mi][ni], 0, 0, 0);                           \
    __builtin_amdgcn_s_setprio(0);                                           \
    __builtin_amdgcn_s_barrier();                                            \
  }

__global__ __launch_bounds__(512, 2) void gemm_kernel(
    const float* __restrict__ x, const float* __restrict__ h,
    const float* __restrict__ W, const float* __restrict__ bias,
    unsigned short* __restrict__ C) {
  __shared__ __align__(16) char lds[131072];

  const int tid = threadIdx.x;
  const int w = tid >> 6, l = tid & 63;
  const int wm = w >> 2, wn = w & 3;            // 2 x 4 wave grid

  // XCD-aware swizzle: 256 blocks, 8 XCDs, each XCD owns a 4x8 rect.
  const int bid = blockIdx.x;
  const int xcd = bid & 7, li = bid >> 3;
  const int by = (xcd & 3) * 4 + (li >> 3);
  const int bx = ((xcd >> 2) << 3) + (li & 7);
  const int bm = by * 256, bn = bx * 256;

  // reader: swizzled ds_read lane offset within a 1KB subtile
  const int lofs = (((l & 15) * 64) + ((l >> 4) * 16)) ^ ((l & 8) << 2);
  // writer: swizzled ds_write lane offset (same stored layout as lofs)
  const int wofs = (l * 16) ^ (l & 32);

  // staging source: lane covers row l>>2 (16 rows/subtile), col chunk (l&3)*8
  const int srow = l >> 2, scol = (l & 3) * 8;
  // wave w stages A rows 32w..32w+31 (2 subtiles) and B rows 32w..32w+31
  const int ar0 = bm + 32 * w + srow, ar1 = ar0 + 16;
  const float* pAx0 = x + (size_t)ar0 * 1024 + scol;
  const float* pAx1 = x + (size_t)ar1 * 1024 + scol;
  const float* pAh0 = h + (size_t)ar0 * 1024 + scol;
  const float* pAh1 = h + (size_t)ar1 * 1024 + scol;
  const float* pB0 = W + (size_t)(bn + 32 * w + srow) * K_DIM + scol;
  const float* pB1 = W + (size_t)(bn + 32 * w + 16 + srow) * K_DIM + scol;

  float4 LA00, LA01, LA10, LA11, LB00, LB01, LB10, LB11;

  f32x4 acc[8][4];
#pragma unroll
  for (int i = 0; i < 8; ++i)
#pragma unroll
    for (int j = 0; j < 4; ++j) acc[i][j] = (f32x4)0.0f;

  // ---- prologue: loads(0) -> buf0; loads(1) in flight ----
  ISSUE_LOADS(0);
  asm volatile("s_waitcnt vmcnt(0)" ::: "memory");
  __builtin_amdgcn_sched_barrier(0);
  CVT_WRITE(0);
  __builtin_amdgcn_sched_barrier(0);
  ISSUE_LOADS(1);
  asm volatile("s_waitcnt lgkmcnt(0)" ::: "memory");
  __builtin_amdgcn_s_barrier();

  for (int t = 0; t < NT32; t += 4) {
    TILE1(t + 0, 0);
    TILE1(t + 1, 1);
    TILE1(t + 2, 2);
    TILE1(t + 3, 3);
  }

  // ---- epilogue: +bias (fp32), convert to bf16, store ----
  const int lm = l & 15, lq = l >> 4;
  float bv[4];
#pragma unroll
  for (int ni = 0; ni < 4; ++ni) bv[ni] = bias[bn + wn * 64 + ni * 16 + lm];
  unsigned short* Cb = C + (size_t)(bm + wm * 128) * N_DIM + bn + wn * 64;
#pragma unroll
  for (int mi = 0; mi < 8; ++mi)
#pragma unroll
    for (int j = 0; j < 4; ++j) {
      const size_t rofs = (size_t)(mi * 16 + lq * 4 + j) * N_DIM;
#pragma unroll
      for (int ni = 0; ni < 4; ++ni)
        Cb[rofs + ni * 16 + lm] = f2bf(acc[mi][ni][j] + bv[ni]);
    }
}

// -------- fused LN + activations + cell update -----------------------------
__device__ __forceinline__ float2 blk_sum2(float s, float q, float* red,
                                           int wid, int lane) {
#pragma unroll
  for (int o = 32; o >= 1; o >>= 1) {
    s += __shfl_xor(s, o, 64);
    q += __shfl_xor(q, o, 64);
  }
  __syncthreads();
  if (lane == 0) { red[wid * 2] = s; red[wid * 2 + 1] = q; }
  __syncthreads();
  s = red[0] + red[2] + red[4] + red[6];
  q = red[1] + red[3] + red[5] + red[7];
  return make_float2(s, q);
}

__device__ __forceinline__ float sigmoidf_(float x) {
  return 1.0f / (1.0f + __expf(-x));
}
__device__ __forceinline__ float tanhf_(float x) {
  return 1.0f - 2.0f / (__expf(2.0f * x) + 1.0f);
}

__global__ __launch_bounds__(256) void ln_lstm_kernel(
    const unsigned short* __restrict__ gates, const float* __restrict__ cprev,
    const float* __restrict__ g_i, const float* __restrict__ b_i,
    const float* __restrict__ g_f, const float* __restrict__ b_f,
    const float* __restrict__ g_g, const float* __restrict__ b_g,
    const float* __restrict__ g_o, const float* __restrict__ b_o,
    const float* __restrict__ g_c, const float* __restrict__ b_c,
    float* __restrict__ out) {
  const int b = blockIdx.x;
  const int t = threadIdx.x;
  const int wid = t >> 6, lane = t & 63;
  __shared__ float red[8];

  const unsigned short* grow = gates + (size_t)b * N_DIM;
  const int c0 = t * 4;

  float v[4][4];
#pragma unroll
  for (int g = 0; g < 4; g++) {
    ushort4 raw = *(const ushort4*)(grow + g * 1024 + c0);
    v[g][0] = bf2f(raw.x); v[g][1] = bf2f(raw.y);
    v[g][2] = bf2f(raw.z); v[g][3] = bf2f(raw.w);
  }

  const float4 gamma[4] = {*(const float4*)(g_i + c0), *(const float4*)(g_f + c0),
                           *(const float4*)(g_g + c0), *(const float4*)(g_o + c0)};
  const float4 beta[4]  = {*(const float4*)(b_i + c0), *(const float4*)(b_f + c0),
                           *(const float4*)(b_g + c0), *(const float4*)(b_o + c0)};

  float a[4][4];
#pragma unroll
  for (int g = 0; g < 4; g++) {
    float s = v[g][0] + v[g][1] + v[g][2] + v[g][3];
    float q = v[g][0]*v[g][0] + v[g][1]*v[g][1] + v[g][2]*v[g][2] + v[g][3]*v[g][3];
    float2 r = blk_sum2(s, q, red, wid, lane);
    float mu = r.x * (1.0f / 1024.0f);
    float var = r.y * (1.0f / 1024.0f) - mu * mu;
    float inv = rsqrtf(var + 1e-5f);
    const float* gm = (const float*)&gamma[g];
    const float* bt = (const float*)&beta[g];
#pragma unroll
    for (int j = 0; j < 4; j++) {
      float n = (v[g][j] - mu) * inv * gm[j] + bt[j];
      a[g][j] = (g == 2) ? tanhf_(n) : sigmoidf_(n);
    }
  }

  float4 cp = *(const float4*)(cprev + (size_t)b * 1024 + c0);
  const float* cpe = (const float*)&cp;
  float cn[4];
#pragma unroll
  for (int j = 0; j < 4; j++)
    cn[j] = a[1][j] * cpe[j] + a[0][j] * a[2][j];

  {
    float s = cn[0] + cn[1] + cn[2] + cn[3];
    float q = cn[0]*cn[0] + cn[1]*cn[1] + cn[2]*cn[2] + cn[3]*cn[3];
    float2 r = blk_sum2(s, q, red, wid, lane);
    float mu = r.x * (1.0f / 1024.0f);
    float var = r.y * (1.0f / 1024.0f) - mu * mu;
    float inv = rsqrtf(var + 1e-5f);
    float4 gm = *(const float4*)(g_c + c0);
    float4 bt = *(const float4*)(b_c + c0);
    const float* gme = (const float*)&gm;
    const float* bte = (const float*)&bt;
    float hn[4];
#pragma unroll
    for (int j = 0; j < 4; j++) {
      float n = (cn[j] - mu) * inv * gme[j] + bte[j];
      hn[j] = a[3][j] * tanhf_(n);
    }
    *(float4*)(out + (size_t)b * 1024 + c0) = make_float4(hn[0], hn[1], hn[2], hn[3]);
    *(float4*)(out + (size_t)B_ROWS * H_DIM + (size_t)b * 1024 + c0) =
        make_float4(cn[0], cn[1], cn[2], cn[3]);
  }
}

// ---------------------------------------------------------------------------
extern "C" void kernel_launch(void* const* d_in, const int* in_sizes, int n_in,
                              void* d_out, int out_size, void* d_ws,
                              size_t ws_size, hipStream_t stream) {
  const float* x    = (const float*)d_in[0];
  const float* h    = (const float*)d_in[1];
  const float* c    = (const float*)d_in[2];
  const float* W    = (const float*)d_in[3];
  const float* bias = (const float*)d_in[4];
  const float* ln_i_g = (const float*)d_in[5];
  const float* ln_i_b = (const float*)d_in[6];
  const float* ln_f_g = (const float*)d_in[7];
  const float* ln_f_b = (const float*)d_in[8];
  const float* ln_g_g = (const float*)d_in[9];
  const float* ln_g_b = (const float*)d_in[10];
  const float* ln_o_g = (const float*)d_in[11];
  const float* ln_o_b = (const float*)d_in[12];
  const float* ln_c_g = (const float*)d_in[13];
  const float* ln_c_b = (const float*)d_in[14];

  // workspace: gates bf16 (32MB) only — no pack buffers
  unsigned short* gates = (unsigned short*)d_ws;

  dim3 ggrid(256);
  gemm_kernel<<<ggrid, 512, 0, stream>>>(x, h, W, bias, gates);

  ln_lstm_kernel<<<B_ROWS, 256, 0, stream>>>(
      gates, c, ln_i_g, ln_i_b, ln_f_g, ln_f_b, ln_g_g, ln_g_b,
      ln_o_g, ln_o_b, ln_c_g, ln_c_b, (float*)d_out);
}